// Round 8
// baseline (314.831 us; speedup 1.0000x reference)
//
#include <hip/hip_runtime.h>
#include <hip/hip_fp16.h>

// MDLSTM 64x64 grid, B=32, I=64, O=128.  (R5-best config + init-merge + gemm occupancy)
//   K1 init:  blocks 0-15: lut[p] = cell index for diagonal-packed order p
//             blocks 16-20: wt[g][o][k] (f16) = -W_g[k][o] * log2(e)
//   K2 gemm:  pre-activations gx~ = -(x@W+b)*log2e, TILED plane layout:
//               plane01[pt][w][pl] : dword = (f0,f1) f16 pair  (tile 2 MiB)
//               plane23[pt][w][pl] : dword = (i,o)  f16 pair   (tile 2 MiB)
//               plane4 [pt][w][pl] : f16 = c                   (tile 1 MiB)
//             Block (pt,b) writes one contiguous 64 KiB region per plane.
//             __launch_bounds__(256,8): 8 blocks/CU (VGPR 64, LDS 18.4K) to
//             deepen outstanding stores (R3/R4: all pipes idle, occ 28%).
//   K3 recur: one wave per w=(b,o), lane j = column j, anti-diagonal sweep.
//             Merged-rcp cell math (8 trans/step), DPP wave_shr lane shift,
//             4-deep diagonal prefetch, tiled per-lane offsets.
//   K4 transpose: plane4 tiled -> out [cell][w] f32, 64p x 256w tile.
// Workspace: planes 64+64+32 = 160 MiB | lut 16 KiB | wt 80 KiB.

#define P23_OFF  ((size_t)64 << 20)
#define P4_OFF   ((size_t)128 << 20)
#define GX_BYTES ((size_t)160 << 20)
#define LOG2E    1.4426950408889634f

typedef __attribute__((ext_vector_type(8))) _Float16 half8;
typedef __attribute__((ext_vector_type(2))) __fp16 fp16x2;
typedef __attribute__((ext_vector_type(4))) float f32x4;
typedef __attribute__((ext_vector_type(2))) float f32x2;

__device__ __forceinline__ unsigned pkrtz(float a, float b) {
    union { fp16x2 h; unsigned u; } c;
    c.h = __builtin_amdgcn_cvt_pkrtz(a, b);
    return c.u;
}

__device__ __forceinline__ int diag_off(int d) {
    return (d < 64) ? ((d * (d + 1)) >> 1) : (4096 - (((127 - d) * (128 - d)) >> 1));
}

// blocks 0-15: lut. blocks 16-20: weight transform.
__global__ __launch_bounds__(256) void init_kernel(
    int* __restrict__ lut,
    const float* __restrict__ wf, const float* __restrict__ wi,
    const float* __restrict__ wo, const float* __restrict__ wc,
    _Float16* __restrict__ wt)
{
    if (blockIdx.x < 16) {
        int t = blockIdx.x * 256 + threadIdx.x;   // 0..4095 = i*64+j
        int i = t >> 6, j = t & 63;
        int d = i + j;
        int jmin = (d > 63) ? (d - 63) : 0;
        lut[diag_off(d) + j - jmin] = t;
    } else {
        const int g = blockIdx.x - 16;
        const float* W = (g == 0) ? wf : (g == 1) ? (wf + 8192)
                       : (g == 2) ? wi : (g == 3) ? wo : wc;
        const int t = threadIdx.x;
        const int o = t >> 1, k0 = (t & 1) * 32;
        _Float16 buf[32];
#pragma unroll
        for (int k = 0; k < 32; ++k)
            buf[k] = (_Float16)(-W[(k0 + k) * 128 + o] * LOG2E);
        _Float16* dst = wt + ((size_t)g * 128 + o) * 64 + k0;
#pragma unroll
        for (int q = 0; q < 4; ++q) *(half8*)(dst + q * 8) = *(half8*)(buf + q * 8);
    }
}

// MFMA GEMM: tile 128p x 128o, K=64. grid (32 p-tiles, 32 b). 8 blocks/CU.
__global__ __launch_bounds__(256, 8) void gemm_kernel(
    const float* __restrict__ x, const _Float16* __restrict__ wt,
    const float* __restrict__ biasf, const float* __restrict__ biasi,
    const float* __restrict__ biaso, const float* __restrict__ biasc,
    const int* __restrict__ lut, char* __restrict__ gx)
{
    __shared__ _Float16 As[128][72];     // [p][k]
    const int t  = threadIdx.x;
    const int pt = blockIdx.x;           // p-tile index (p0 = pt*128)
    const int p0 = pt * 128;
    const int b  = blockIdx.y;

    // stage A: x rows (via lut) -> f16, As[p][k]
    {
        int r = t >> 1, k0 = (t & 1) * 32;
        int cell = lut[p0 + r];
        const float* xr = x + ((size_t)cell * 32 + b) * 64 + k0;
#pragma unroll
        for (int it = 0; it < 4; ++it) {
            float4 v0 = *(const float4*)(xr + it * 8);
            float4 v1 = *(const float4*)(xr + it * 8 + 4);
            half8 h;
            h[0] = (_Float16)v0.x; h[1] = (_Float16)v0.y;
            h[2] = (_Float16)v0.z; h[3] = (_Float16)v0.w;
            h[4] = (_Float16)v1.x; h[5] = (_Float16)v1.y;
            h[6] = (_Float16)v1.z; h[7] = (_Float16)v1.w;
            *(half8*)&As[r][k0 + it * 8] = h;
        }
    }
    __syncthreads();

    const int lane = t & 63;
    const int wv   = __builtin_amdgcn_readfirstlane(t >> 6);
    const int m    = lane & 15;
    const int quad = lane >> 4;
    const int o0   = wv * 32 + m;       // of=0 column
    const int o1   = o0 + 16;           // of=1 column

    // tiled-plane byte bases for this block's contiguous 64 KiB region
    const size_t t01 = (size_t)pt * 2097152 + (size_t)(b * 128) * 512;
    const size_t t4b = (size_t)pt * 1048576 + (size_t)(b * 128) * 256;

    // -------- pair phase: gates (ga, gb) -> packed dword plane --------
    // per-pf: 8 MFMA -> pack -> two 16B stores (acc live range = one pf)
    auto pair_phase = [&](const _Float16* wga, const _Float16* wgb,
                          const float* bA, const float* bB, char* plane) {
        half8 ba0[2], ba1[2], bb0[2], bb1[2];
#pragma unroll
        for (int kh = 0; kh < 2; ++kh) {
            ba0[kh] = *(const half8*)(wga + o0 * 64 + kh * 32 + quad * 8);
            ba1[kh] = *(const half8*)(wga + o1 * 64 + kh * 32 + quad * 8);
            bb0[kh] = *(const half8*)(wgb + o0 * 64 + kh * 32 + quad * 8);
            bb1[kh] = *(const half8*)(wgb + o1 * 64 + kh * 32 + quad * 8);
        }
        float sA0 = -bA[o0] * LOG2E, sA1 = -bA[o1] * LOG2E;
        float sB0 = -bB[o0] * LOG2E, sB1 = -bB[o1] * LOG2E;
        char* base = plane + t01;
#pragma unroll
        for (int pf = 0; pf < 8; ++pf) {
            half8 af0 = *(const half8*)&As[pf * 16 + m][quad * 8];
            half8 af1 = *(const half8*)&As[pf * 16 + m][32 + quad * 8];
            f32x4 aA0 = {}, aA1 = {}, aB0 = {}, aB1 = {};
            aA0 = __builtin_amdgcn_mfma_f32_16x16x32_f16(af0, ba0[0], aA0, 0, 0, 0);
            aA0 = __builtin_amdgcn_mfma_f32_16x16x32_f16(af1, ba0[1], aA0, 0, 0, 0);
            aA1 = __builtin_amdgcn_mfma_f32_16x16x32_f16(af0, ba1[0], aA1, 0, 0, 0);
            aA1 = __builtin_amdgcn_mfma_f32_16x16x32_f16(af1, ba1[1], aA1, 0, 0, 0);
            aB0 = __builtin_amdgcn_mfma_f32_16x16x32_f16(af0, bb0[0], aB0, 0, 0, 0);
            aB0 = __builtin_amdgcn_mfma_f32_16x16x32_f16(af1, bb0[1], aB0, 0, 0, 0);
            aB1 = __builtin_amdgcn_mfma_f32_16x16x32_f16(af0, bb1[0], aB1, 0, 0, 0);
            aB1 = __builtin_amdgcn_mfma_f32_16x16x32_f16(af1, bb1[1], aB1, 0, 0, 0);
            uint4 st0, st1;
            st0.x = pkrtz(aA0[0] + sA0, aB0[0] + sB0);
            st0.y = pkrtz(aA0[1] + sA0, aB0[1] + sB0);
            st0.z = pkrtz(aA0[2] + sA0, aB0[2] + sB0);
            st0.w = pkrtz(aA0[3] + sA0, aB0[3] + sB0);
            *(uint4*)(base + (size_t)o0 * 512 + quad * 16 + pf * 64) = st0;
            st1.x = pkrtz(aA1[0] + sA1, aB1[0] + sB1);
            st1.y = pkrtz(aA1[1] + sA1, aB1[1] + sB1);
            st1.z = pkrtz(aA1[2] + sA1, aB1[2] + sB1);
            st1.w = pkrtz(aA1[3] + sA1, aB1[3] + sB1);
            *(uint4*)(base + (size_t)o1 * 512 + quad * 16 + pf * 64) = st1;
        }
    };
    pair_phase(wt,            wt + 8192,     biasf, biasf + 128, gx);
    pair_phase(wt + 2 * 8192, wt + 3 * 8192, biasi, biaso,       gx + P23_OFF);

    // -------- single phase: gate c -> f16 plane4 --------
    {
        const _Float16* wg = wt + 4 * 8192;
        half8 b0[2], b1[2];
#pragma unroll
        for (int kh = 0; kh < 2; ++kh) {
            b0[kh] = *(const half8*)(wg + o0 * 64 + kh * 32 + quad * 8);
            b1[kh] = *(const half8*)(wg + o1 * 64 + kh * 32 + quad * 8);
        }
        float s0 = -biasc[o0] * LOG2E, s1 = -biasc[o1] * LOG2E;
        char* base = gx + P4_OFF + t4b;
#pragma unroll
        for (int pf = 0; pf < 8; ++pf) {
            half8 af0 = *(const half8*)&As[pf * 16 + m][quad * 8];
            half8 af1 = *(const half8*)&As[pf * 16 + m][32 + quad * 8];
            f32x4 ac0 = {}, ac1 = {};
            ac0 = __builtin_amdgcn_mfma_f32_16x16x32_f16(af0, b0[0], ac0, 0, 0, 0);
            ac0 = __builtin_amdgcn_mfma_f32_16x16x32_f16(af1, b0[1], ac0, 0, 0, 0);
            ac1 = __builtin_amdgcn_mfma_f32_16x16x32_f16(af0, b1[0], ac1, 0, 0, 0);
            ac1 = __builtin_amdgcn_mfma_f32_16x16x32_f16(af1, b1[1], ac1, 0, 0, 0);
            uint2 st0, st1;
            st0.x = pkrtz(ac0[0] + s0, ac0[1] + s0);
            st0.y = pkrtz(ac0[2] + s0, ac0[3] + s0);
            *(uint2*)(base + (size_t)o0 * 256 + quad * 8 + pf * 32) = st0;
            st1.x = pkrtz(ac1[0] + s1, ac1[1] + s1);
            st1.y = pkrtz(ac1[2] + s1, ac1[3] + s1);
            *(uint2*)(base + (size_t)o1 * 256 + quad * 8 + pf * 32) = st1;
        }
    }
}

// recurrence: wave w = (b,o); lane j = column j; 127 anti-diagonal steps.
// planes hold z~ = -(xW+b)*log2e; u pre-scaled. Tiled-plane addressing:
// per-lane packed index p -> off01 = (p>>7)<<21 | (p&127)<<2; off4 = off01>>1.
// pb(d) = diag_off(d) - jmin(d); 4-deep prefetch advance:
//   del(d) = pb(d+5)-pb(d+4) = clamp(min(d+5, 122-d), >=0).
// Lane shift via DPP wave_shr:1 (0x138), bound_ctrl zero-fills lane 0.
// Store of diag d reuses offA (the d-offset, computed 4 steps earlier).
// Merged-rcp cell math (8 trans/step):
//   a_g = 1+exp2(z_g);  s = (num*mic + mff)*rcp(mff*mic)
//     with mff=af0*af1, mic=ai*ac, num = s_up*af1 + s_left*af0
//   h = og*tanh(s) = (e2-1)*rcp(ao*(e2+1)),  e2 = exp2(min(2*log2e*s, 80))
__global__ __launch_bounds__(256) void recur_kernel(
    char* __restrict__ gx,
    const float* __restrict__ uf, const float* __restrict__ ui,
    const float* __restrict__ uo, const float* __restrict__ uc)
{
    const int lane = threadIdx.x & 63;
    const int w = __builtin_amdgcn_readfirstlane(blockIdx.x * 4 + (threadIdx.x >> 6));
    const int o = w & 127;

    // pair coefficients: A = (f0,f1) plane, B = (i,o) plane, scalar = c plane
    const f32x2 nAu = { -uf[o]       * LOG2E, -uf[256 + o] * LOG2E };
    const f32x2 nAl = { -uf[128 + o] * LOG2E, -uf[384 + o] * LOG2E };
    const f32x2 nBu = { -ui[o]       * LOG2E, -uo[o]       * LOG2E };
    const f32x2 nBl = { -ui[128 + o] * LOG2E, -uo[128 + o] * LOG2E };
    const float nc0 = -uc[o] * LOG2E, nc1 = -uc[128 + o] * LOG2E;

    // uniform per-w byte bases into the tiled planes
    const char* b01 = gx + (size_t)w * 512;
    const char* b23 = gx + P23_OFF + (size_t)w * 512;
    const char* b4  = gx + P4_OFF + (size_t)w * 256;
    char*       s4  = gx + P4_OFF + (size_t)w * 256;

    // per-lane tiled byte offset for packed dword index p = pb + lane
    auto offs = [&](int pb) -> int {
        int p = pb + lane;
        return ((p >> 7) << 21) + ((p & 127) << 2);
    };

#define LD3(off_, v01_, v23_, v4_) { \
    __half2 h01 = *(const __half2*)(b01 + (off_)); \
    __half2 h23 = *(const __half2*)(b23 + (off_)); \
    _Float16 h4 = *(const _Float16*)(b4 + ((off_) >> 1)); \
    v01_ = (f32x2){ __low2float(h01), __high2float(h01) }; \
    v23_ = (f32x2){ __low2float(h23), __high2float(h23) }; \
    v4_ = (float)h4; }

    // 4-deep pipeline: g0 = diag d, g1..g3 = d+1..d+3, t = incoming d+4
    int offA = offs(0);                 // pb(0)=0
    int offB = offs(1);                 // pb(1)=1
    int offC = offs(3);                 // pb(2)=3
    int offD = offs(6);                 // pb(3)=6
    f32x2 g0a, g0b; float g0c;
    f32x2 g1a, g1b; float g1c;
    f32x2 g2a, g2b; float g2c;
    f32x2 g3a, g3b; float g3c;
    LD3(offA, g0a, g0b, g0c);
    LD3(offB, g1a, g1b, g1c);
    LD3(offC, g2a, g2b, g2c);
    LD3(offD, g3a, g3b, g3c);
    int pb = 10;                        // pb(4) = diag_off(4)

    float s_prev = 0.f, h_prev = 0.f;

#pragma unroll 4
    for (int d = 0; d < 127; ++d) {
        int offE = offs(pb);                    // diag d+4
        f32x2 t01, t23; float t4;
        LD3(offE, t01, t23, t4);                // prefetch diag d+4
        int del = min(d + 5, 122 - d); del = max(del, 0);
        pb += del;

        // s_left/h_left: lane j-1 -> lane j, lane 0 -> 0 (bound_ctrl)
        int slb = __builtin_amdgcn_update_dpp(
            0, __float_as_int(s_prev), 0x138, 0xf, 0xf, true);
        int hlb = __builtin_amdgcn_update_dpp(
            0, __float_as_int(h_prev), 0x138, 0xf, 0xf, true);
        float sl = __int_as_float(slb), hl = __int_as_float(hlb);

        // z preactivations as packed f32 pairs (v_pk_fma_f32)
        f32x2 hu2 = { h_prev, h_prev };
        f32x2 hl2 = { hl, hl };
        f32x2 zA = __builtin_elementwise_fma(hu2, nAu,
                     __builtin_elementwise_fma(hl2, nAl, g0a));
        f32x2 zB = __builtin_elementwise_fma(hu2, nBu,
                     __builtin_elementwise_fma(hl2, nBl, g0b));
        float zc = fmaf(h_prev, nc0, fmaf(hl, nc1, g0c));

        f32x2 eA = { __builtin_amdgcn_exp2f(zA.x), __builtin_amdgcn_exp2f(zA.y) };
        f32x2 eB = { __builtin_amdgcn_exp2f(zB.x), __builtin_amdgcn_exp2f(zB.y) };
        float ec = __builtin_amdgcn_exp2f(zc);
        f32x2 aA = eA + 1.f;              // (1+Ef0, 1+Ef1)
        f32x2 aB = eB + 1.f;              // (1+Ei,  1+Eo)
        float acg = ec + 1.f;             //  1+Ec

        float mff  = aA.x * aA.y;
        float mic  = aB.x * acg;
        float den  = mff * mic;
        float num  = fmaf(s_prev, aA.y, sl * aA.x);
        float num2 = fmaf(num, mic, mff);
        float s    = num2 * __builtin_amdgcn_rcpf(den);

        float t2 = fminf(s * (2.f * LOG2E), 80.f);
        float e2 = __builtin_amdgcn_exp2f(t2);
        float hd = fmaf(aB.y, e2, aB.y);          // ao*(e2+1)
        float h  = (e2 - 1.f) * __builtin_amdgcn_rcpf(hd);

        bool act = (unsigned)(d - lane) < 64u;   // i = d-j in [0,64)
        if (act) *(_Float16*)(s4 + (offA >> 1)) = (_Float16)s;  // dead slot

        s_prev = act ? s : 0.f;
        h_prev = act ? h : 0.f;
        g0a = g1a; g0b = g1b; g0c = g1c;
        g1a = g2a; g1b = g2b; g1c = g2c;
        g2a = g3a; g2b = g3b; g2c = g3c;
        g3a = t01; g3b = t23; g3c = t4;
        offA = offB; offB = offC; offC = offD; offD = offE;
    }
#undef LD3
}

// plane4 tiled [pt][w][pl] f16 -> out[cell][w] f32.  Tile: 64 p x 256 w.
__global__ __launch_bounds__(256) void transpose_kernel(
    const char* __restrict__ gx, const int* __restrict__ lut,
    float* __restrict__ out)
{
    __shared__ _Float16 T[256][80];
    const int t  = threadIdx.x;
    const int p0 = blockIdx.x * 64;
    const int w0 = blockIdx.y * 256;
    const int pt  = p0 >> 7;
    const int pl0 = p0 & 127;
    const char* p4t = gx + P4_OFF + (size_t)pt * 1048576;
#pragma unroll
    for (int it = 0; it < 8; ++it) {
        int wl = it * 32 + (t >> 3), pl = (t & 7) * 8;
        *(half8*)&T[wl][pl] =
            *(const half8*)(p4t + (size_t)(w0 + wl) * 256 + (pl0 + pl) * 2);
    }
    __syncthreads();
    float* ob = out + w0 + t;
#pragma unroll 4
    for (int p = 0; p < 64; ++p) {
        int cell = lut[p0 + p];                 // block-uniform -> scalar load
        ob[(size_t)cell * 4096] = (float)T[t][p];
    }
}

extern "C" void kernel_launch(void* const* d_in, const int* in_sizes, int n_in,
                              void* d_out, int out_size, void* d_ws, size_t ws_size,
                              hipStream_t stream) {
    const float* x     = (const float*)d_in[0];
    const float* wf    = (const float*)d_in[1];
    const float* uf    = (const float*)d_in[2];
    const float* biasf = (const float*)d_in[3];
    const float* wi    = (const float*)d_in[4];
    const float* ui    = (const float*)d_in[5];
    const float* biasi = (const float*)d_in[6];
    const float* wo    = (const float*)d_in[7];
    const float* uo    = (const float*)d_in[8];
    const float* biaso = (const float*)d_in[9];
    const float* wc    = (const float*)d_in[10];
    const float* uc    = (const float*)d_in[11];
    const float* biasc = (const float*)d_in[12];
    float* out = (float*)d_out;

    char*     gx  = (char*)d_ws;
    int*      lut = (int*)(gx + GX_BYTES);
    _Float16* wt  = (_Float16*)((char*)lut + 16384);

    init_kernel<<<21, 256, 0, stream>>>(lut, wf, wi, wo, wc, wt);
    gemm_kernel<<<dim3(32, 32), 256, 0, stream>>>(
        x, wt, biasf, biasi, biaso, biasc, lut, gx);
    recur_kernel<<<1024, 256, 0, stream>>>(gx, uf, ui, uo, uc);
    transpose_kernel<<<dim3(64, 16), 256, 0, stream>>>(gx, lut, out);
}

// Round 9
// 229.308 us; speedup vs baseline: 1.3730x; 1.3730x over previous
//
#include <hip/hip_runtime.h>
#include <hip/hip_fp16.h>

// MDLSTM 64x64 grid, B=32, I=64, O=128.  (R5-best config + init-merge + transpose pad fix)
//   K1 init:  blocks 0-15: lut[p] = cell index for diagonal-packed order p
//             blocks 16-20: wt[g][o][k] (f16) = -W_g[k][o] * log2(e)
//   K2 gemm:  pre-activations gx~ = -(x@W+b)*log2e, TILED plane layout:
//               plane01[pt][w][pl] : dword = (f0,f1) f16 pair  (tile 2 MiB)
//               plane23[pt][w][pl] : dword = (i,o)  f16 pair   (tile 2 MiB)
//               plane4 [pt][w][pl] : f16 = c                   (tile 1 MiB)
//             Block (pt,b) writes one contiguous 64 KiB region per plane.
//             __launch_bounds__(256,4): VGPR 64, no spills.  ((256,8) forced
//             VGPR->32 -> scratch spill storm: FETCH 38->102MB, gemm 2x slower.)
//   K3 recur: one wave per w=(b,o), lane j = column j, anti-diagonal sweep.
//             Merged-rcp cell math (8 trans/step), DPP wave_shr lane shift,
//             4-deep diagonal prefetch, tiled per-lane offsets. ~65us plateau.
//   K4 transpose: plane4 tiled -> out [cell][w] f32, 64p x 256w tile.
//             LDS pad 80->82 f16 (row = 41 dwords, odd): write-phase column
//             read T[t][p] was (40t)%32 -> 4 banks = 16-way conflict; 41
//             is coprime with 32 -> 2 lanes/bank = free.
// Workspace: planes 64+64+32 = 160 MiB | lut 16 KiB | wt 80 KiB.

#define P23_OFF  ((size_t)64 << 20)
#define P4_OFF   ((size_t)128 << 20)
#define GX_BYTES ((size_t)160 << 20)
#define LOG2E    1.4426950408889634f

typedef __attribute__((ext_vector_type(8))) _Float16 half8;
typedef __attribute__((ext_vector_type(2))) __fp16 fp16x2;
typedef __attribute__((ext_vector_type(4))) float f32x4;
typedef __attribute__((ext_vector_type(2))) float f32x2;

__device__ __forceinline__ unsigned pkrtz(float a, float b) {
    union { fp16x2 h; unsigned u; } c;
    c.h = __builtin_amdgcn_cvt_pkrtz(a, b);
    return c.u;
}

__device__ __forceinline__ int diag_off(int d) {
    return (d < 64) ? ((d * (d + 1)) >> 1) : (4096 - (((127 - d) * (128 - d)) >> 1));
}

// blocks 0-15: lut. blocks 16-20: weight transform.
__global__ __launch_bounds__(256) void init_kernel(
    int* __restrict__ lut,
    const float* __restrict__ wf, const float* __restrict__ wi,
    const float* __restrict__ wo, const float* __restrict__ wc,
    _Float16* __restrict__ wt)
{
    if (blockIdx.x < 16) {
        int t = blockIdx.x * 256 + threadIdx.x;   // 0..4095 = i*64+j
        int i = t >> 6, j = t & 63;
        int d = i + j;
        int jmin = (d > 63) ? (d - 63) : 0;
        lut[diag_off(d) + j - jmin] = t;
    } else {
        const int g = blockIdx.x - 16;
        const float* W = (g == 0) ? wf : (g == 1) ? (wf + 8192)
                       : (g == 2) ? wi : (g == 3) ? wo : wc;
        const int t = threadIdx.x;
        const int o = t >> 1, k0 = (t & 1) * 32;
        _Float16 buf[32];
#pragma unroll
        for (int k = 0; k < 32; ++k)
            buf[k] = (_Float16)(-W[(k0 + k) * 128 + o] * LOG2E);
        _Float16* dst = wt + ((size_t)g * 128 + o) * 64 + k0;
#pragma unroll
        for (int q = 0; q < 4; ++q) *(half8*)(dst + q * 8) = *(half8*)(buf + q * 8);
    }
}

// MFMA GEMM: tile 128p x 128o, K=64. grid (32 p-tiles, 32 b). 4 blocks/CU.
__global__ __launch_bounds__(256, 4) void gemm_kernel(
    const float* __restrict__ x, const _Float16* __restrict__ wt,
    const float* __restrict__ biasf, const float* __restrict__ biasi,
    const float* __restrict__ biaso, const float* __restrict__ biasc,
    const int* __restrict__ lut, char* __restrict__ gx)
{
    __shared__ _Float16 As[128][72];     // [p][k]
    const int t  = threadIdx.x;
    const int pt = blockIdx.x;           // p-tile index (p0 = pt*128)
    const int p0 = pt * 128;
    const int b  = blockIdx.y;

    // stage A: x rows (via lut) -> f16, As[p][k]
    {
        int r = t >> 1, k0 = (t & 1) * 32;
        int cell = lut[p0 + r];
        const float* xr = x + ((size_t)cell * 32 + b) * 64 + k0;
#pragma unroll
        for (int it = 0; it < 4; ++it) {
            float4 v0 = *(const float4*)(xr + it * 8);
            float4 v1 = *(const float4*)(xr + it * 8 + 4);
            half8 h;
            h[0] = (_Float16)v0.x; h[1] = (_Float16)v0.y;
            h[2] = (_Float16)v0.z; h[3] = (_Float16)v0.w;
            h[4] = (_Float16)v1.x; h[5] = (_Float16)v1.y;
            h[6] = (_Float16)v1.z; h[7] = (_Float16)v1.w;
            *(half8*)&As[r][k0 + it * 8] = h;
        }
    }
    __syncthreads();

    const int lane = t & 63;
    const int wv   = __builtin_amdgcn_readfirstlane(t >> 6);
    const int m    = lane & 15;
    const int quad = lane >> 4;
    const int o0   = wv * 32 + m;       // of=0 column
    const int o1   = o0 + 16;           // of=1 column

    // tiled-plane byte bases for this block's contiguous 64 KiB region
    const size_t t01 = (size_t)pt * 2097152 + (size_t)(b * 128) * 512;
    const size_t t4b = (size_t)pt * 1048576 + (size_t)(b * 128) * 256;

    // -------- pair phase: gates (ga, gb) -> packed dword plane --------
    // per-pf: 8 MFMA -> pack -> two 16B stores (acc live range = one pf)
    auto pair_phase = [&](const _Float16* wga, const _Float16* wgb,
                          const float* bA, const float* bB, char* plane) {
        half8 ba0[2], ba1[2], bb0[2], bb1[2];
#pragma unroll
        for (int kh = 0; kh < 2; ++kh) {
            ba0[kh] = *(const half8*)(wga + o0 * 64 + kh * 32 + quad * 8);
            ba1[kh] = *(const half8*)(wga + o1 * 64 + kh * 32 + quad * 8);
            bb0[kh] = *(const half8*)(wgb + o0 * 64 + kh * 32 + quad * 8);
            bb1[kh] = *(const half8*)(wgb + o1 * 64 + kh * 32 + quad * 8);
        }
        float sA0 = -bA[o0] * LOG2E, sA1 = -bA[o1] * LOG2E;
        float sB0 = -bB[o0] * LOG2E, sB1 = -bB[o1] * LOG2E;
        char* base = plane + t01;
#pragma unroll
        for (int pf = 0; pf < 8; ++pf) {
            half8 af0 = *(const half8*)&As[pf * 16 + m][quad * 8];
            half8 af1 = *(const half8*)&As[pf * 16 + m][32 + quad * 8];
            f32x4 aA0 = {}, aA1 = {}, aB0 = {}, aB1 = {};
            aA0 = __builtin_amdgcn_mfma_f32_16x16x32_f16(af0, ba0[0], aA0, 0, 0, 0);
            aA0 = __builtin_amdgcn_mfma_f32_16x16x32_f16(af1, ba0[1], aA0, 0, 0, 0);
            aA1 = __builtin_amdgcn_mfma_f32_16x16x32_f16(af0, ba1[0], aA1, 0, 0, 0);
            aA1 = __builtin_amdgcn_mfma_f32_16x16x32_f16(af1, ba1[1], aA1, 0, 0, 0);
            aB0 = __builtin_amdgcn_mfma_f32_16x16x32_f16(af0, bb0[0], aB0, 0, 0, 0);
            aB0 = __builtin_amdgcn_mfma_f32_16x16x32_f16(af1, bb0[1], aB0, 0, 0, 0);
            aB1 = __builtin_amdgcn_mfma_f32_16x16x32_f16(af0, bb1[0], aB1, 0, 0, 0);
            aB1 = __builtin_amdgcn_mfma_f32_16x16x32_f16(af1, bb1[1], aB1, 0, 0, 0);
            uint4 st0, st1;
            st0.x = pkrtz(aA0[0] + sA0, aB0[0] + sB0);
            st0.y = pkrtz(aA0[1] + sA0, aB0[1] + sB0);
            st0.z = pkrtz(aA0[2] + sA0, aB0[2] + sB0);
            st0.w = pkrtz(aA0[3] + sA0, aB0[3] + sB0);
            *(uint4*)(base + (size_t)o0 * 512 + quad * 16 + pf * 64) = st0;
            st1.x = pkrtz(aA1[0] + sA1, aB1[0] + sB1);
            st1.y = pkrtz(aA1[1] + sA1, aB1[1] + sB1);
            st1.z = pkrtz(aA1[2] + sA1, aB1[2] + sB1);
            st1.w = pkrtz(aA1[3] + sA1, aB1[3] + sB1);
            *(uint4*)(base + (size_t)o1 * 512 + quad * 16 + pf * 64) = st1;
        }
    };
    pair_phase(wt,            wt + 8192,     biasf, biasf + 128, gx);
    pair_phase(wt + 2 * 8192, wt + 3 * 8192, biasi, biaso,       gx + P23_OFF);

    // -------- single phase: gate c -> f16 plane4 --------
    {
        const _Float16* wg = wt + 4 * 8192;
        half8 b0[2], b1[2];
#pragma unroll
        for (int kh = 0; kh < 2; ++kh) {
            b0[kh] = *(const half8*)(wg + o0 * 64 + kh * 32 + quad * 8);
            b1[kh] = *(const half8*)(wg + o1 * 64 + kh * 32 + quad * 8);
        }
        float s0 = -biasc[o0] * LOG2E, s1 = -biasc[o1] * LOG2E;
        char* base = gx + P4_OFF + t4b;
#pragma unroll
        for (int pf = 0; pf < 8; ++pf) {
            half8 af0 = *(const half8*)&As[pf * 16 + m][quad * 8];
            half8 af1 = *(const half8*)&As[pf * 16 + m][32 + quad * 8];
            f32x4 ac0 = {}, ac1 = {};
            ac0 = __builtin_amdgcn_mfma_f32_16x16x32_f16(af0, b0[0], ac0, 0, 0, 0);
            ac0 = __builtin_amdgcn_mfma_f32_16x16x32_f16(af1, b0[1], ac0, 0, 0, 0);
            ac1 = __builtin_amdgcn_mfma_f32_16x16x32_f16(af0, b1[0], ac1, 0, 0, 0);
            ac1 = __builtin_amdgcn_mfma_f32_16x16x32_f16(af1, b1[1], ac1, 0, 0, 0);
            uint2 st0, st1;
            st0.x = pkrtz(ac0[0] + s0, ac0[1] + s0);
            st0.y = pkrtz(ac0[2] + s0, ac0[3] + s0);
            *(uint2*)(base + (size_t)o0 * 256 + quad * 8 + pf * 32) = st0;
            st1.x = pkrtz(ac1[0] + s1, ac1[1] + s1);
            st1.y = pkrtz(ac1[2] + s1, ac1[3] + s1);
            *(uint2*)(base + (size_t)o1 * 256 + quad * 8 + pf * 32) = st1;
        }
    }
}

// recurrence: wave w = (b,o); lane j = column j; 127 anti-diagonal steps.
// planes hold z~ = -(xW+b)*log2e; u pre-scaled. Tiled-plane addressing:
// per-lane packed index p -> off01 = (p>>7)<<21 | (p&127)<<2; off4 = off01>>1.
// pb(d) = diag_off(d) - jmin(d); 4-deep prefetch advance:
//   del(d) = pb(d+5)-pb(d+4) = clamp(min(d+5, 122-d), >=0).
// Lane shift via DPP wave_shr:1 (0x138), bound_ctrl zero-fills lane 0.
// Store of diag d reuses offA (the d-offset, computed 4 steps earlier).
// Merged-rcp cell math (8 trans/step):
//   a_g = 1+exp2(z_g);  s = (num*mic + mff)*rcp(mff*mic)
//     with mff=af0*af1, mic=ai*ac, num = s_up*af1 + s_left*af0
//   h = og*tanh(s) = (e2-1)*rcp(ao*(e2+1)),  e2 = exp2(min(2*log2e*s, 80))
__global__ __launch_bounds__(256) void recur_kernel(
    char* __restrict__ gx,
    const float* __restrict__ uf, const float* __restrict__ ui,
    const float* __restrict__ uo, const float* __restrict__ uc)
{
    const int lane = threadIdx.x & 63;
    const int w = __builtin_amdgcn_readfirstlane(blockIdx.x * 4 + (threadIdx.x >> 6));
    const int o = w & 127;

    // pair coefficients: A = (f0,f1) plane, B = (i,o) plane, scalar = c plane
    const f32x2 nAu = { -uf[o]       * LOG2E, -uf[256 + o] * LOG2E };
    const f32x2 nAl = { -uf[128 + o] * LOG2E, -uf[384 + o] * LOG2E };
    const f32x2 nBu = { -ui[o]       * LOG2E, -uo[o]       * LOG2E };
    const f32x2 nBl = { -ui[128 + o] * LOG2E, -uo[128 + o] * LOG2E };
    const float nc0 = -uc[o] * LOG2E, nc1 = -uc[128 + o] * LOG2E;

    // uniform per-w byte bases into the tiled planes
    const char* b01 = gx + (size_t)w * 512;
    const char* b23 = gx + P23_OFF + (size_t)w * 512;
    const char* b4  = gx + P4_OFF + (size_t)w * 256;
    char*       s4  = gx + P4_OFF + (size_t)w * 256;

    // per-lane tiled byte offset for packed dword index p = pb + lane
    auto offs = [&](int pb) -> int {
        int p = pb + lane;
        return ((p >> 7) << 21) + ((p & 127) << 2);
    };

#define LD3(off_, v01_, v23_, v4_) { \
    __half2 h01 = *(const __half2*)(b01 + (off_)); \
    __half2 h23 = *(const __half2*)(b23 + (off_)); \
    _Float16 h4 = *(const _Float16*)(b4 + ((off_) >> 1)); \
    v01_ = (f32x2){ __low2float(h01), __high2float(h01) }; \
    v23_ = (f32x2){ __low2float(h23), __high2float(h23) }; \
    v4_ = (float)h4; }

    // 4-deep pipeline: g0 = diag d, g1..g3 = d+1..d+3, t = incoming d+4
    int offA = offs(0);                 // pb(0)=0
    int offB = offs(1);                 // pb(1)=1
    int offC = offs(3);                 // pb(2)=3
    int offD = offs(6);                 // pb(3)=6
    f32x2 g0a, g0b; float g0c;
    f32x2 g1a, g1b; float g1c;
    f32x2 g2a, g2b; float g2c;
    f32x2 g3a, g3b; float g3c;
    LD3(offA, g0a, g0b, g0c);
    LD3(offB, g1a, g1b, g1c);
    LD3(offC, g2a, g2b, g2c);
    LD3(offD, g3a, g3b, g3c);
    int pb = 10;                        // pb(4) = diag_off(4)

    float s_prev = 0.f, h_prev = 0.f;

#pragma unroll 4
    for (int d = 0; d < 127; ++d) {
        int offE = offs(pb);                    // diag d+4
        f32x2 t01, t23; float t4;
        LD3(offE, t01, t23, t4);                // prefetch diag d+4
        int del = min(d + 5, 122 - d); del = max(del, 0);
        pb += del;

        // s_left/h_left: lane j-1 -> lane j, lane 0 -> 0 (bound_ctrl)
        int slb = __builtin_amdgcn_update_dpp(
            0, __float_as_int(s_prev), 0x138, 0xf, 0xf, true);
        int hlb = __builtin_amdgcn_update_dpp(
            0, __float_as_int(h_prev), 0x138, 0xf, 0xf, true);
        float sl = __int_as_float(slb), hl = __int_as_float(hlb);

        // z preactivations as packed f32 pairs (v_pk_fma_f32)
        f32x2 hu2 = { h_prev, h_prev };
        f32x2 hl2 = { hl, hl };
        f32x2 zA = __builtin_elementwise_fma(hu2, nAu,
                     __builtin_elementwise_fma(hl2, nAl, g0a));
        f32x2 zB = __builtin_elementwise_fma(hu2, nBu,
                     __builtin_elementwise_fma(hl2, nBl, g0b));
        float zc = fmaf(h_prev, nc0, fmaf(hl, nc1, g0c));

        f32x2 eA = { __builtin_amdgcn_exp2f(zA.x), __builtin_amdgcn_exp2f(zA.y) };
        f32x2 eB = { __builtin_amdgcn_exp2f(zB.x), __builtin_amdgcn_exp2f(zB.y) };
        float ec = __builtin_amdgcn_exp2f(zc);
        f32x2 aA = eA + 1.f;              // (1+Ef0, 1+Ef1)
        f32x2 aB = eB + 1.f;              // (1+Ei,  1+Eo)
        float acg = ec + 1.f;             //  1+Ec

        float mff  = aA.x * aA.y;
        float mic  = aB.x * acg;
        float den  = mff * mic;
        float num  = fmaf(s_prev, aA.y, sl * aA.x);
        float num2 = fmaf(num, mic, mff);
        float s    = num2 * __builtin_amdgcn_rcpf(den);

        float t2 = fminf(s * (2.f * LOG2E), 80.f);
        float e2 = __builtin_amdgcn_exp2f(t2);
        float hd = fmaf(aB.y, e2, aB.y);          // ao*(e2+1)
        float h  = (e2 - 1.f) * __builtin_amdgcn_rcpf(hd);

        bool act = (unsigned)(d - lane) < 64u;   // i = d-j in [0,64)
        if (act) *(_Float16*)(s4 + (offA >> 1)) = (_Float16)s;  // dead slot

        s_prev = act ? s : 0.f;
        h_prev = act ? h : 0.f;
        g0a = g1a; g0b = g1b; g0c = g1c;
        g1a = g2a; g1b = g2b; g1c = g2c;
        g2a = g3a; g2b = g3b; g2c = g3c;
        g3a = t01; g3b = t23; g3c = t4;
        offA = offB; offB = offC; offC = offD; offD = offE;
    }
#undef LD3
}

// plane4 tiled [pt][w][pl] f16 -> out[cell][w] f32.  Tile: 64 p x 256 w.
// LDS row = 82 f16 = 41 dwords (odd): column read T[t][p] hits all 32 banks
// (2 lanes/bank = free). Pad 80 (40 dwords) was a 16-way conflict.
__global__ __launch_bounds__(256) void transpose_kernel(
    const char* __restrict__ gx, const int* __restrict__ lut,
    float* __restrict__ out)
{
    __shared__ _Float16 T[256][82];
    const int t  = threadIdx.x;
    const int p0 = blockIdx.x * 64;
    const int w0 = blockIdx.y * 256;
    const int pt  = p0 >> 7;
    const int pl0 = p0 & 127;
    const char* p4t = gx + P4_OFF + (size_t)pt * 1048576;
#pragma unroll
    for (int it = 0; it < 8; ++it) {
        int wl = it * 32 + (t >> 3), pl = (t & 7) * 8;
        *(half8*)&T[wl][pl] =
            *(const half8*)(p4t + (size_t)(w0 + wl) * 256 + (pl0 + pl) * 2);
    }
    __syncthreads();
    float* ob = out + w0 + t;
#pragma unroll 4
    for (int p = 0; p < 64; ++p) {
        int cell = lut[p0 + p];                 // block-uniform -> scalar load
        ob[(size_t)cell * 4096] = (float)T[t][p];
    }
}

extern "C" void kernel_launch(void* const* d_in, const int* in_sizes, int n_in,
                              void* d_out, int out_size, void* d_ws, size_t ws_size,
                              hipStream_t stream) {
    const float* x     = (const float*)d_in[0];
    const float* wf    = (const float*)d_in[1];
    const float* uf    = (const float*)d_in[2];
    const float* biasf = (const float*)d_in[3];
    const float* wi    = (const float*)d_in[4];
    const float* ui    = (const float*)d_in[5];
    const float* biasi = (const float*)d_in[6];
    const float* wo    = (const float*)d_in[7];
    const float* uo    = (const float*)d_in[8];
    const float* biaso = (const float*)d_in[9];
    const float* wc    = (const float*)d_in[10];
    const float* uc    = (const float*)d_in[11];
    const float* biasc = (const float*)d_in[12];
    float* out = (float*)d_out;

    char*     gx  = (char*)d_ws;
    int*      lut = (int*)(gx + GX_BYTES);
    _Float16* wt  = (_Float16*)((char*)lut + 16384);

    init_kernel<<<21, 256, 0, stream>>>(lut, wf, wi, wo, wc, wt);
    gemm_kernel<<<dim3(32, 32), 256, 0, stream>>>(
        x, wt, biasf, biasi, biaso, biasc, lut, gx);
    recur_kernel<<<1024, 256, 0, stream>>>(gx, uf, ui, uo, uc);
    transpose_kernel<<<dim3(64, 16), 256, 0, stream>>>(gx, lut, out);
}